// Round 2
// baseline (135.515 us; speedup 1.0000x reference)
//
#include <hip/hip_runtime.h>
#include <cfloat>

// Problem constants: M=N=64 grid, DIM=512, B=4096, SIGMA=32
#define DIMK 512
#define MN   4096
#define BATCH 4096
#define NGRP 1024   // 4-column groups per row

typedef _Float16 half8_t __attribute__((ext_vector_type(8)));
typedef _Float16 half4_t __attribute__((ext_vector_type(4)));
typedef float f32x4 __attribute__((ext_vector_type(4)));

// async global->LDS, 16B per lane; LDS dest is wave-uniform base + lane*16
#define GLD16(gp, lp) __builtin_amdgcn_global_load_lds( \
    (const __attribute__((address_space(1))) void*)(gp), \
    (__attribute__((address_space(3))) void*)(lp), 16, 0, 0)

// ---------------------------------------------------------------------------
// Convert: X,W fp32 -> f16 RTN + exact fp32 row norms. (unchanged)
// ---------------------------------------------------------------------------
__global__ __launch_bounds__(256) void convert_kernel(
        const float* __restrict__ X, const float* __restrict__ W,
        _Float16* __restrict__ Xh, _Float16* __restrict__ Wh,
        float* __restrict__ w2, float* __restrict__ xnorm) {
    const int blk  = blockIdx.x;
    const int t    = threadIdx.x;
    const bool isW = blk >= 1024;
    const float* src = isW ? W : X;
    _Float16* dst  = isW ? Wh : Xh;
    const int rblk = isW ? blk - 1024 : blk;
    const size_t idx = (size_t)rblk * 2048 + (size_t)t * 8;

    float4 v0 = *(const float4*)(src + idx);
    float4 v1 = *(const float4*)(src + idx + 4);
    float v[8] = {v0.x, v0.y, v0.z, v0.w, v1.x, v1.y, v1.z, v1.w};
    half8_t hv;
    float s = 0.f;
#pragma unroll
    for (int e = 0; e < 8; e++) {
        s += v[e] * v[e];
        hv[e] = (_Float16)v[e];
    }
    *(half8_t*)(dst + idx) = hv;
#pragma unroll
    for (int o = 32; o > 0; o >>= 1) s += __shfl_down(s, o);
    if ((t & 63) == 0) {
        int row = rblk * 4 + (t >> 6);
        if (isW) w2[row] = s;
        else     xnorm[row] = __fsqrt_rn(s);
    }
}

// ---------------------------------------------------------------------------
// Score GEMM v3: 256x256 tile, 8 waves (2m x 4n), BK=32, 4-deep LDS ring
// (4 x [A 16KB | B 16KB] = 128 KiB). Loads for tile t issued during tile
// t-3 (~6 slots ahead -> vmcnt(8) gate never blocks). ONE s_barrier per
// K-tile: it jointly guarantees (a) tile t's loads landed (every wave
// passed its own vmcnt gate) and (b) all waves finished reading tile t-1's
// buffer (lgkmcnt(0) preceded their arrival), so staging into buf[(t+3)&3]
// = buf[(t-1)&3] after the barrier is safe. Within a tile waves drift
// freely: 12 ds_read_b128 up front, lgkmcnt(4)-gated first MFMA cluster,
// lgkmcnt(0)-gated second, setprio around each (T4+T5). Fully unrolled so
// all waitcnt immediates are literals. Accumulation order (K ascending in
// 32-slices) identical to v2 -> bit-identical group-mins.
// ---------------------------------------------------------------------------
#define MFMA16(A0, A1, A2, A3, R) \
    do { \
        acc[(R)+0][0] = __builtin_amdgcn_mfma_f32_16x16x32_f16(A0, b0, acc[(R)+0][0], 0, 0, 0); \
        acc[(R)+0][1] = __builtin_amdgcn_mfma_f32_16x16x32_f16(A0, b1, acc[(R)+0][1], 0, 0, 0); \
        acc[(R)+0][2] = __builtin_amdgcn_mfma_f32_16x16x32_f16(A0, b2, acc[(R)+0][2], 0, 0, 0); \
        acc[(R)+0][3] = __builtin_amdgcn_mfma_f32_16x16x32_f16(A0, b3, acc[(R)+0][3], 0, 0, 0); \
        acc[(R)+1][0] = __builtin_amdgcn_mfma_f32_16x16x32_f16(A1, b0, acc[(R)+1][0], 0, 0, 0); \
        acc[(R)+1][1] = __builtin_amdgcn_mfma_f32_16x16x32_f16(A1, b1, acc[(R)+1][1], 0, 0, 0); \
        acc[(R)+1][2] = __builtin_amdgcn_mfma_f32_16x16x32_f16(A1, b2, acc[(R)+1][2], 0, 0, 0); \
        acc[(R)+1][3] = __builtin_amdgcn_mfma_f32_16x16x32_f16(A1, b3, acc[(R)+1][3], 0, 0, 0); \
        acc[(R)+2][0] = __builtin_amdgcn_mfma_f32_16x16x32_f16(A2, b0, acc[(R)+2][0], 0, 0, 0); \
        acc[(R)+2][1] = __builtin_amdgcn_mfma_f32_16x16x32_f16(A2, b1, acc[(R)+2][1], 0, 0, 0); \
        acc[(R)+2][2] = __builtin_amdgcn_mfma_f32_16x16x32_f16(A2, b2, acc[(R)+2][2], 0, 0, 0); \
        acc[(R)+2][3] = __builtin_amdgcn_mfma_f32_16x16x32_f16(A2, b3, acc[(R)+2][3], 0, 0, 0); \
        acc[(R)+3][0] = __builtin_amdgcn_mfma_f32_16x16x32_f16(A3, b0, acc[(R)+3][0], 0, 0, 0); \
        acc[(R)+3][1] = __builtin_amdgcn_mfma_f32_16x16x32_f16(A3, b1, acc[(R)+3][1], 0, 0, 0); \
        acc[(R)+3][2] = __builtin_amdgcn_mfma_f32_16x16x32_f16(A3, b2, acc[(R)+3][2], 0, 0, 0); \
        acc[(R)+3][3] = __builtin_amdgcn_mfma_f32_16x16x32_f16(A3, b3, acc[(R)+3][3], 0, 0, 0); \
    } while (0)

__global__ __launch_bounds__(512, 2) void score_kernel(
        const _Float16* __restrict__ Xh, const _Float16* __restrict__ Wh,
        const float* __restrict__ w2, float* __restrict__ Gm /* = d_out */) {
    // 4-deep ring: [buf][A/B][16 rg x (64 lanes x 8 f16)] = 4 x 32 KiB
    __shared__ __align__(16) _Float16 lds[4][2][8192];

    const int t    = threadIdx.x;
    const int lane = t & 63;
    const int w    = t >> 6;        // wave 0..7
    const int wm   = w >> 2;        // m-half (0..1) -> 128 rows
    const int wn   = w & 3;         // n-quarter (0..3) -> 64 cols

    // XCD-bijective swizzle: id%8 -> XCD; each XCD owns a 4(m) x 8(n) rect
    const int id  = blockIdx.y * 16 + blockIdx.x;
    const int xcd = id & 7;
    const int li  = id >> 3;                 // 0..31
    const int bm  = (xcd >> 1) * 4 + (li >> 3);
    const int bn  = (xcd & 1) * 8 + (li & 7);
    const int m0  = bm * 256;
    const int n0  = bn * 256;

    // staging map: thread t -> frag (rg = c*8 + (t>>6), lane = t&63),
    // i.e. global row = c*128 + (t>>6)*16 + (t&15), k-oct = (t>>4)&3.
    const int srow = (t >> 6) * 16 + (t & 15);
    const int skof = ((t >> 4) & 3) * 8;
    const _Float16* gA = Xh + (size_t)(m0 + srow) * DIMK + skof;
    const _Float16* gB = Wh + (size_t)(n0 + srow) * DIMK + skof;
    const int ldst = t * 8;

#define STG_A(bf, kt, c) GLD16(gA + (size_t)(c) * (128 * DIMK) + (kt) * 32, &lds[bf][0][(c) * 4096 + ldst])
#define STG_B(bf, kt, c) GLD16(gB + (size_t)(c) * (128 * DIMK) + (kt) * 32, &lds[bf][1][(c) * 4096 + ldst])
#define LDA(bf, rg) (*(const half8_t*)(&lds[bf][0][(rg) * 512 + lane * 8]))
#define LDB(bf, rg) (*(const half8_t*)(&lds[bf][1][(rg) * 512 + lane * 8]))

    f32x4 acc[8][4];
#pragma unroll
    for (int i = 0; i < 8; i++)
#pragma unroll
        for (int j = 0; j < 4; j++) acc[i][j] = (f32x4){0.f, 0.f, 0.f, 0.f};

    // prologue: stage tiles 0,1,2 into ring slots 0,1,2 (12 loads, tile order)
    STG_A(0, 0, 0); STG_A(0, 0, 1); STG_B(0, 0, 0); STG_B(0, 0, 1);
    STG_A(1, 1, 0); STG_A(1, 1, 1); STG_B(1, 1, 0); STG_B(1, 1, 1);
    STG_A(2, 2, 0); STG_A(2, 2, 1); STG_B(2, 2, 0); STG_B(2, 2, 1);

#pragma unroll
    for (int kt = 0; kt < 16; ++kt) {
        const int bf = kt & 3;
        const int nb = (kt + 3) & 3;

        // gate: drain tile kt's 4 loads (issued 3 tiles ago; no-op wait in
        // steady state). Outstanding before wait: kt..kt+2 fully = 12.
        if (kt <= 13)      { asm volatile("s_waitcnt vmcnt(8)" ::: "memory"); }
        else if (kt == 14) { asm volatile("s_waitcnt vmcnt(4)" ::: "memory"); }
        else               { asm volatile("s_waitcnt vmcnt(0)" ::: "memory"); }
        __builtin_amdgcn_sched_barrier(0);
        __builtin_amdgcn_s_barrier();   // ONLY barrier this tile (see header)

        if (kt <= 12) { STG_A(nb, kt + 3, 0); STG_A(nb, kt + 3, 1); }

        // 12 ds_read_b128: cluster-1 operands first (oldest 8), then a4-7
        half8_t a0 = LDA(bf, wm * 8 + 0), a1 = LDA(bf, wm * 8 + 1);
        half8_t a2 = LDA(bf, wm * 8 + 2), a3 = LDA(bf, wm * 8 + 3);
        half8_t b0 = LDB(bf, wn * 4 + 0), b1 = LDB(bf, wn * 4 + 1);
        half8_t b2 = LDB(bf, wn * 4 + 2), b3 = LDB(bf, wn * 4 + 3);
        half8_t a4 = LDA(bf, wm * 8 + 4), a5 = LDA(bf, wm * 8 + 5);
        half8_t a6 = LDA(bf, wm * 8 + 6), a7 = LDA(bf, wm * 8 + 7);

        if (kt <= 12) { STG_B(nb, kt + 3, 0); STG_B(nb, kt + 3, 1); }

        asm volatile("s_waitcnt lgkmcnt(4)" ::: "memory");  // a0-3,b0-3 landed
        __builtin_amdgcn_sched_barrier(0);
        __builtin_amdgcn_s_setprio(1);
        MFMA16(a0, a1, a2, a3, 0);
        __builtin_amdgcn_s_setprio(0);

        asm volatile("s_waitcnt lgkmcnt(0)" ::: "memory");  // a4-7 landed
        __builtin_amdgcn_sched_barrier(0);
        __builtin_amdgcn_s_setprio(1);
        MFMA16(a4, a5, a6, a7, 4);
        __builtin_amdgcn_s_setprio(0);
    }

    // ---- 4-col group mins -> f16. D layout: col=lane&15, row=(lane>>4)*4+v ----
    const int q   = lane >> 4;
    const int cl  = lane & 15;
    const int gb  = (n0 >> 2) + wn * 16;
    float w2v[4];
#pragma unroll
    for (int j = 0; j < 4; j++) w2v[j] = w2[n0 + wn * 64 + j * 16 + cl];
#pragma unroll
    for (int ai = 0; ai < 8; ai++)
#pragma unroll
        for (int v = 0; v < 4; v++) {
            const int row = m0 + wm * 128 + ai * 16 + q * 4 + v;
            _Float16* grow = (_Float16*)Gm + (size_t)row * 8192 + gb;
#pragma unroll
            for (int j = 0; j < 4; j++) {
                float s = w2v[j] - 2.0f * acc[ai][j][v];
                s = fminf(s, __shfl_xor(s, 1));
                s = fminf(s, __shfl_xor(s, 2));
                if ((cl & 3) == 0) grow[j * 4 + (cl >> 2)] = (_Float16)s;
            }
        }
}

// ---------------------------------------------------------------------------
// Epilogue: per-row f16 group-min screen + barrier-free exact fp32 rescore +
// separable Gaussian row write. (unchanged)
// ---------------------------------------------------------------------------
__global__ __launch_bounds__(256) void epilogue_kernel(
        const float* __restrict__ w2, const float* __restrict__ xnorm,
        const float* __restrict__ X, const float* __restrict__ W,
        const int* __restrict__ decay_p, const int* __restrict__ it_p,
        float* out) {
    __shared__ float xs[512];
    __shared__ int   list[NGRP];
    __shared__ int   cnt;
    __shared__ float wmin[4];
    __shared__ float svv[4];
    __shared__ int   svi[4];
    __shared__ float tab[128];
    const int row  = blockIdx.x;
    const int t    = threadIdx.x;
    const int lane = t & 63;
    const int w    = t >> 6;

    {
        float2 xv = *(const float2*)(X + (size_t)row * DIMK + t * 2);
        xs[2 * t]     = xv.x;
        xs[2 * t + 1] = xv.y;
    }
    if (t == 0) cnt = 0;

    // f16 group-mins: 4 per thread (8B coalesced)
    half4_t gmh = *((const half4_t*)((const _Float16*)out + (size_t)row * 8192) + t);
    float gme[4] = {(float)gmh[0], (float)gmh[1], (float)gmh[2], (float)gmh[3]};
    float g = fminf(fminf(gme[0], gme[1]), fminf(gme[2], gme[3]));
#pragma unroll
    for (int mask = 1; mask <= 32; mask <<= 1)
        g = fminf(g, __shfl_xor(g, mask));
    if (lane == 0) wmin[w] = g;
    __syncthreads();
    const float gmin = fminf(fminf(wmin[0], wmin[1]), fminf(wmin[2], wmin[3]));
    const float tau  = gmin + 2.0f * (0.0222f * xnorm[row] + 0.25f);

    // collect qualifying groups (unordered; explicit col tie-break later)
#pragma unroll
    for (int e = 0; e < 4; e++)
        if (gme[e] <= tau) list[atomicAdd(&cnt, 1)] = t * 4 + e;
    __syncthreads();
    const int total = cnt;            // >= 1 always (gmin's group qualifies)

    // barrier-free exact rescore: wave w owns groups w, w+4, w+8, ...
    float mbv = FLT_MAX;
    int   mbi = 0x7FFFFFFF;
    for (int idx = w; idx < total; idx += 4) {
        const int gid = list[idx];
#pragma unroll
        for (int cj = 0; cj < 4; cj++) {
            const int col = gid * 4 + cj;
            const float* wr = W + (size_t)col * DIMK;
            float p = 0.f;
#pragma unroll
            for (int e = 0; e < 8; e++) p += xs[lane * 8 + e] * wr[lane * 8 + e];
#pragma unroll
            for (int mask = 1; mask <= 32; mask <<= 1) p += __shfl_xor(p, mask);
            float s = w2[col] - 2.0f * p;
            if (s < mbv || (s == mbv && col < mbi)) { mbv = s; mbi = col; }
        }
    }
    if (lane == 0) { svv[w] = mbv; svi[w] = mbi; }
    __syncthreads();
    // merge (uniform across all threads; no extra sync needed)
    float sbv = svv[0]; int sbi = svi[0];
#pragma unroll
    for (int k = 1; k < 4; k++) {
        float s = svv[k]; int c = svi[k];
        if (s < sbv || (s == sbv && c < sbi)) { sbv = s; sbi = c; }
    }

    // separable Gaussian tables + row write (overwrites group-mins)
    const float lr  = __expf(-(float)(*it_p) / (float)(*decay_p));
    const float so  = 32.0f * lr;          // SIGMA = 32
    const float inv = 1.0f / (so * so);
    const int rr = sbi >> 6, cc = sbi & 63;
    if (t < 64) {
        float d = (float)(t - rr);
        tab[t] = __expf(-d * d * inv);
    } else if (t < 128) {
        float d = (float)(t - 64 - cc);
        tab[t] = __expf(-d * d * inv);
    }
    __syncthreads();
    const float* er = tab;
    const float* ec = tab + 64;
    f32x4* orow = (f32x4*)(out + (size_t)row * 4096);
#pragma unroll
    for (int qq = 0; qq < 4; qq++) {
        int f  = qq * 256 + t;
        int i  = f >> 4;
        int j0 = (f & 15) * 4;
        float e = er[i];
        f32x4 o = {e * ec[j0], e * ec[j0 + 1], e * ec[j0 + 2], e * ec[j0 + 3]};
        __builtin_nontemporal_store(o, orow + f);
    }
}

// ---------------------------------------------------------------------------
extern "C" void kernel_launch(void* const* d_in, const int* in_sizes, int n_in,
                              void* d_out, int out_size, void* d_ws, size_t ws_size,
                              hipStream_t stream) {
    const float* X       = (const float*)d_in[0];   // [4096,512]
    const float* W       = (const float*)d_in[1];   // [4096,512]
    const int*   decay_p = (const int*)d_in[3];
    const int*   it_p    = (const int*)d_in[4];
    float* out = (float*)d_out;                     // doubles as group-min scratch

    // ws: Xh (4MB) | Wh (4MB) | w2 16KB | xnorm 16KB
    _Float16* Xh = (_Float16*)d_ws;
    _Float16* Wh = Xh + (size_t)BATCH * DIMK;
    float*    w2 = (float*)(Wh + (size_t)MN * DIMK);
    float*    xn = w2 + MN;

    convert_kernel<<<2048, 256, 0, stream>>>(X, W, Xh, Wh, w2, xn);
    score_kernel<<<dim3(16, 16), 512, 0, stream>>>(Xh, Wh, w2, out);
    epilogue_kernel<<<BATCH, 256, 0, stream>>>(w2, xn, X, W, decay_p, it_p, out);
}